// Round 9
// baseline (59.160 us; speedup 1.0000x reference)
//
#include <hip/hip_runtime.h>
#include <math.h>

#define BATCH 8
#define TDIM 2048
#define DDIM 512
#define SLOTB 2048       // bytes per packed row slot: [512B fp8 xq | 1024B gelu bf16 | pad]
#define NT 16            // number of 128-row tiles per batch
#define NTRI (NT*(NT+1)/2)
#define SCALE_E8M0 123   // 2^-4: compensates the x16 pre-scale on each operand

typedef unsigned short u16;
typedef float f32x4 __attribute__((ext_vector_type(4)));
typedef u16 u16x8 __attribute__((ext_vector_type(8)));
typedef int i32x4 __attribute__((ext_vector_type(4)));
typedef int i32x8 __attribute__((ext_vector_type(8)));

// fast tanh via single v_exp_f32: tanh(u) = 1 - 2/(exp(2u)+1)
__device__ __forceinline__ float tanh_fast(float u) {
    float e = __expf(2.0f * u);
    return 1.0f - 2.0f / (e + 1.0f);
}

__device__ __forceinline__ float gelu_f(float x) {
    const float c = 0.7978845608028654f; // sqrt(2/pi)
    return 0.5f * x * (1.0f + tanh_fast(c * (x + 0.044715f * x * x * x)));
}

__device__ __forceinline__ u16 f2bf(float f) {
    unsigned u = __float_as_uint(f);
    return (u16)((u + 0x7FFFu + ((u >> 16) & 1u)) >> 16); // RNE, no NaN inputs
}
__device__ __forceinline__ float bf2f(u16 h) {
    return __uint_as_float(((unsigned)h) << 16);
}

__device__ __forceinline__ float wave_sum(float v) {
    #pragma unroll
    for (int s = 1; s < 64; s <<= 1) v += __shfl_xor(v, s, 64);
    return v;
}

__device__ __forceinline__ void load_lds16(const void* g, void* l) {
    __builtin_amdgcn_global_load_lds(
        (const __attribute__((address_space(1))) void*)g,
        (__attribute__((address_space(3))) void*)l, 16, 0, 0);
}

// ---------------- kernel 1: norms, cos_ema, fp8 xq (x_n*16) + bf16 gelu ----------------
__global__ __launch_bounds__(256) void prep_kernel(
    const float* __restrict__ x, const float* __restrict__ ema,
    char* __restrict__ slots, float* __restrict__ cosema)
{
    const int wave = threadIdx.x >> 6;
    const int lane = threadIdx.x & 63;
    const int row  = blockIdx.x * 4 + wave; // 0 .. B*T-1

    const float* xr = x + (size_t)row * DDIM + lane * 8;
    float4 v0 = *reinterpret_cast<const float4*>(xr);
    float4 v1 = *reinterpret_cast<const float4*>(xr + 4);
    const float* er = ema + lane * 8;
    float4 e0 = *reinterpret_cast<const float4*>(er);
    float4 e1 = *reinterpret_cast<const float4*>(er + 4);

    float vx[8] = {v0.x,v0.y,v0.z,v0.w,v1.x,v1.y,v1.z,v1.w};
    float ve[8] = {e0.x,e0.y,e0.z,e0.w,e1.x,e1.y,e1.z,e1.w};
    float gg[8];

    float ssx=0.f, ssg=0.f, dge=0.f, sse=0.f;
    #pragma unroll
    for (int j=0;j<8;++j) {
        float xv = vx[j];
        ssx += xv*xv;
        float gv = gelu_f(xv);
        gg[j] = gv;
        ssg += gv*gv;
        dge += gv*ve[j];
        sse += ve[j]*ve[j];
    }
    ssx = wave_sum(ssx); ssg = wave_sum(ssg);
    dge = wave_sum(dge); sse = wave_sum(sse);

    // quantize x_n * 16 to e4m3 (MX scale 2^-4 per operand restores the product)
    float invx16 = 16.0f / fmaxf(sqrtf(ssx), 1e-12f);
    float s[8];
    #pragma unroll
    for (int j=0;j<8;++j) s[j] = vx[j] * invx16;
    int q0 = __builtin_amdgcn_cvt_pk_fp8_f32(s[0], s[1], 0, false);
    q0     = __builtin_amdgcn_cvt_pk_fp8_f32(s[2], s[3], q0, true);
    int q1 = __builtin_amdgcn_cvt_pk_fp8_f32(s[4], s[5], 0, false);
    q1     = __builtin_amdgcn_cvt_pk_fp8_f32(s[6], s[7], q1, true);

    char* rowb = slots + (size_t)row * SLOTB;
    reinterpret_cast<int*>(rowb)[lane*2]     = q0;   // xq bytes [0,512)
    reinterpret_cast<int*>(rowb)[lane*2 + 1] = q1;

    u16x8 hg;
    #pragma unroll
    for (int j=0;j<8;++j) hg[j] = f2bf(gg[j]);
    *reinterpret_cast<u16x8*>(rowb + 512 + lane * 16) = hg;  // gelu bytes [512,1536)

    if (lane == 0) {
        float c = dge / (fmaxf(sqrtf(ssg), 1e-12f) * fmaxf(sqrtf(sse), 1e-12f));
        c = fminf(fmaxf(c, -1.0f), 1.0f);
        cosema[row] = c;
    }
}

// -------- kernel 2: per-batch Xn*Xn^T row-max via MX-fp8 K=128, full-K in LDS --------
// K=512 fp8 = 512 B/row: the ENTIRE 128x128 tile-pair (A+B = 128 KB) fits LDS.
// Single stage phase (16 global_load_lds/thread, source-granule XOR involution
// over 32 granules/row), ONE barrier, then 32 MFMA/wave issue with ds_reads
// freely compiler-pipelined — no inner barriers, no dbuf choreography.
// T1 batch-per-XCD kept (b = blockIdx.x % 8). 512 threads, 8 waves (2x4 over
// the 128x128 output: each wave owns 64 rows x 32 cols).
__global__ __launch_bounds__(512) void simmax_kernel(
    const char* __restrict__ slots, float* __restrict__ part)
{
    __shared__ unsigned char sAll[2][128][512];  // [A|B][row][K bytes]  128 KB
    __shared__ float prow[4][128];
    __shared__ float pcol[2][128];

    const int tid  = threadIdx.x;
    const int lane = tid & 63;
    const int w    = tid >> 6;          // 0..7
    const int wm   = w >> 2, wn = w & 3;

    const int b = blockIdx.x & 7;        // batch == XCD (round-robin dispatch)
    // decode upper-triangular linear index -> (rt, ct), rt <= ct
    int rem = blockIdx.x >> 3, rt = 0;
    while (rem >= (NT - rt)) { rem -= (NT - rt); ++rt; }
    const int ct = rt + rem;

    const char* Ag = slots + ((size_t)b * TDIM + (size_t)rt * 128) * SLOTB;
    const char* Bg = slots + ((size_t)b * TDIM + (size_t)ct * 128) * SLOTB;

    // ---- stage all K: 16 instrs/thread; LDS linear, source pre-swizzled ----
    // slot s = i*512 + w*64 + lane (16B granules); row = s>>5, gs = s&31.
    // LDS slot (row, gs) holds source granule gs ^ (row&7)  (involution).
    const int r0   = w*2 + (lane >> 5);              // row within 16-row stripe
    const int goff = ((lane & 31) ^ (r0 & 7)) * 16;  // pre-swizzled src byte off
    unsigned char* ldsb = &sAll[0][0][0];
    #pragma unroll
    for (int i = 0; i < 16; ++i) {
        const int r = i*16 + r0;                     // 0..255 (A rows then B rows)
        const char* src = (i < 8 ? Ag + (size_t)r * SLOTB
                                 : Bg + (size_t)(r - 128) * SLOTB) + goff;
        load_lds16(src, ldsb + i*8192 + w*1024);
    }
    __syncthreads();   // single drain: whole tile-pair resident

    // ---- compute: 4 K-steps of 128, no barriers ----
    f32x4 zero = {0.f, 0.f, 0.f, 0.f};
    f32x4 acc[4][2];
    #pragma unroll
    for (int m=0;m<4;++m)
        #pragma unroll
        for (int n=0;n<2;++n) acc[m][n] = zero;

    const int roff  = lane & 15;
    const int sw    = roff & 7;          // read-side XOR (row&7 == roff&7)
    const int klane = lane >> 4;
    const unsigned char* Ab = &sAll[0][0][0];
    const unsigned char* Bb = &sAll[1][0][0];

    #pragma unroll
    for (int ks = 0; ks < 4; ++ks) {
        const int g0 = ((ks*8 + 2*klane)     ^ sw) * 16;
        const int g1 = ((ks*8 + 2*klane + 1) ^ sw) * 16;
        i32x8 af[4], bf[2];
        #pragma unroll
        for (int m=0;m<4;++m) {
            const int base = (wm*64 + m*16 + roff) * 512;
            i32x4 lo = *reinterpret_cast<const i32x4*>(Ab + base + g0);
            i32x4 hi = *reinterpret_cast<const i32x4*>(Ab + base + g1);
            af[m] = __builtin_shufflevector(lo, hi, 0,1,2,3,4,5,6,7);
        }
        #pragma unroll
        for (int n=0;n<2;++n) {
            const int base = (wn*32 + n*16 + roff) * 512;
            i32x4 lo = *reinterpret_cast<const i32x4*>(Bb + base + g0);
            i32x4 hi = *reinterpret_cast<const i32x4*>(Bb + base + g1);
            bf[n] = __builtin_shufflevector(lo, hi, 0,1,2,3,4,5,6,7);
        }
        #pragma unroll
        for (int m=0;m<4;++m)
            #pragma unroll
            for (int n=0;n<2;++n)
                acc[m][n] = __builtin_amdgcn_mfma_scale_f32_16x16x128_f8f6f4(
                    af[m], bf[n], acc[m][n], 0, 0,
                    0, SCALE_E8M0, 0, SCALE_E8M0);
    }

    // ---- fused epilogue ----
    // C/D layout (m89/m91, shape-determined per m128): col = lane&15, row = (lane>>4)*4 + reg
    const int gr_base = rt*128 + wm*64;
    const int gc_base = ct*128 + wn*32;
    float rmax[4][4]; // [m][reg]  row-max (diag-masked)
    float cmax[2];    // [n]       col-max (unmasked; used when rt<ct)
    #pragma unroll
    for (int n=0;n<2;++n) cmax[n] = -2.0f;
    #pragma unroll
    for (int m=0;m<4;++m) {
        #pragma unroll
        for (int r=0;r<4;++r) {
            const int grow = gr_base + m*16 + ((lane>>4)<<2) + r;
            float mx = -2.0f;
            #pragma unroll
            for (int n=0;n<2;++n) {
                const int gcol = gc_base + n*16 + (lane & 15);
                float v = acc[m][n][r];
                cmax[n] = fmaxf(cmax[n], v);
                float vm = (grow == gcol) ? -2.0f : v;
                mx = fmaxf(mx, vm);
            }
            rmax[m][r] = mx;
        }
    }
    // row-max: butterfly across the 16-lane column group
    #pragma unroll
    for (int s = 1; s < 16; s <<= 1) {
        #pragma unroll
        for (int m=0;m<4;++m)
            #pragma unroll
            for (int r=0;r<4;++r)
                rmax[m][r] = fmaxf(rmax[m][r], __shfl_xor(rmax[m][r], s, 64));
    }
    if ((lane & 15) == 0) {
        #pragma unroll
        for (int m=0;m<4;++m)
            #pragma unroll
            for (int r=0;r<4;++r)
                prow[wn][wm*64 + m*16 + ((lane>>4)<<2) + r] = rmax[m][r];
    }
    // col-max: butterfly across the 4 row-groups
    #pragma unroll
    for (int s = 16; s < 64; s <<= 1) {
        #pragma unroll
        for (int n=0;n<2;++n)
            cmax[n] = fmaxf(cmax[n], __shfl_xor(cmax[n], s, 64));
    }
    if (lane < 16) {
        #pragma unroll
        for (int n=0;n<2;++n)
            pcol[wm][wn*32 + n*16 + lane] = cmax[n];
    }
    __syncthreads();
    if (tid < 128) {
        float rv = fmaxf(fmaxf(prow[0][tid], prow[1][tid]),
                         fmaxf(prow[2][tid], prow[3][tid]));
        part[((size_t)b*NT + ct)*TDIM + (size_t)rt*128 + tid] = rv;
        if (rt != ct) {
            float cv = fmaxf(pcol[0][tid], pcol[1][tid]);
            part[((size_t)b*NT + rt)*TDIM + (size_t)ct*128 + tid] = cv;
        }
    }
}

// ---------------- kernel 3: gate * cached gelu ----------------
// slots aliases d_out: row r's slot bytes [0,512)=xq (dead), [512,1536)=gelu
// bf16. Each wave reads its own row's gelu then overwrites its own slot with
// the fp32 out row — load-before-store within the wave, race-free.
__global__ __launch_bounds__(256) void finalize_kernel(
    char* slots,
    const float* __restrict__ part, const float* __restrict__ cosema,
    const float* __restrict__ p_log_tau, const float* __restrict__ p_log_sigma,
    const float* __restrict__ p_log_w)
{
    const int wave = threadIdx.x >> 6;
    const int lane = threadIdx.x & 63;
    const int row  = blockIdx.x * 4 + wave;
    const int b = row >> 11;     // /2048
    const int t = row & 2047;

    const float tau   = __expf(p_log_tau[0]);
    const float sigma = log1pf(__expf(p_log_sigma[0])); // softplus
    const float wgt   = log1pf(__expf(p_log_w[0]));

    float nn = -2.0f;
    #pragma unroll
    for (int ctile = 0; ctile < NT; ++ctile)
        nn = fmaxf(nn, part[((size_t)b*NT + ctile)*TDIM + t]);
    nn = fminf(fmaxf(nn, -1.0f), 1.0f);

    const float novelty  = (1.0f - nn) * 0.5f;
    const float surprise = tanh_fast(sigma * novelty);
    const float gate = __expf(-tau * cosema[row]) * (1.0f + wgt * surprise);

    char* rowb = slots + (size_t)row * SLOTB;
    u16x8 hg = *reinterpret_cast<const u16x8*>(rowb + 512 + lane * 16);
    float4 o0, o1;
    o0.x = bf2f(hg[0]) * gate; o0.y = bf2f(hg[1]) * gate;
    o0.z = bf2f(hg[2]) * gate; o0.w = bf2f(hg[3]) * gate;
    o1.x = bf2f(hg[4]) * gate; o1.y = bf2f(hg[5]) * gate;
    o1.z = bf2f(hg[6]) * gate; o1.w = bf2f(hg[7]) * gate;
    float* orow = reinterpret_cast<float*>(rowb) + lane * 8;
    *reinterpret_cast<float4*>(orow)     = o0;
    *reinterpret_cast<float4*>(orow + 4) = o1;
}

extern "C" void kernel_launch(void* const* d_in, const int* in_sizes, int n_in,
                              void* d_out, int out_size, void* d_ws, size_t ws_size,
                              hipStream_t stream) {
    const float* x           = (const float*)d_in[0];
    // d_in[1] = logit_decay (unused by reference)
    const float* p_log_tau   = (const float*)d_in[2];
    const float* p_log_sigma = (const float*)d_in[3];
    const float* p_log_w     = (const float*)d_in[4];
    const float* ema         = (const float*)d_in[5];

    // d_out doubles as scratch: per-row 2048-B slots hold [fp8 xq | bf16 gelu]
    // until finalize overwrites each slot with the fp32 output row.
    char*  slots  = (char*)d_out;                      // B*T*SLOTB = 33.6 MB
    float* part   = (float*)d_ws;                      // B*NT*T*4 = 2 MB
    float* cosema = (float*)((char*)d_ws + (size_t)BATCH*NT*TDIM*sizeof(float));

    prep_kernel<<<dim3(BATCH*TDIM/4), 256, 0, stream>>>(x, ema, slots, cosema);
    simmax_kernel<<<dim3(NTRI*BATCH), 512, 0, stream>>>(slots, part);
    finalize_kernel<<<dim3(BATCH*TDIM/4), 256, 0, stream>>>(
        slots, part, cosema, p_log_tau, p_log_sigma, p_log_w);
}

// Round 10
// 57.297 us; speedup vs baseline: 1.0325x; 1.0325x over previous
//
#include <hip/hip_runtime.h>
#include <math.h>

#define BATCH 8
#define TDIM 2048
#define DDIM 512
#define SLOTB 2048       // bytes per packed row slot: [512B fp8 xq | 1024B gelu bf16 | pad]
#define NT 16            // number of 128-row tiles per batch
#define NUNITS 72        // per batch: sum over rt of ceil((NT-rt)/2)  (2-pair chunks)
#define SCALE_E8M0 123   // 2^-4: compensates the x16 pre-scale on each operand

typedef unsigned short u16;
typedef float f32x4 __attribute__((ext_vector_type(4)));
typedef u16 u16x8 __attribute__((ext_vector_type(8)));
typedef int i32x4 __attribute__((ext_vector_type(4)));
typedef int i32x8 __attribute__((ext_vector_type(8)));

// fast tanh via single v_exp_f32: tanh(u) = 1 - 2/(exp(2u)+1)
__device__ __forceinline__ float tanh_fast(float u) {
    float e = __expf(2.0f * u);
    return 1.0f - 2.0f / (e + 1.0f);
}

__device__ __forceinline__ float gelu_f(float x) {
    const float c = 0.7978845608028654f; // sqrt(2/pi)
    return 0.5f * x * (1.0f + tanh_fast(c * (x + 0.044715f * x * x * x)));
}

__device__ __forceinline__ u16 f2bf(float f) {
    unsigned u = __float_as_uint(f);
    return (u16)((u + 0x7FFFu + ((u >> 16) & 1u)) >> 16); // RNE, no NaN inputs
}
__device__ __forceinline__ float bf2f(u16 h) {
    return __uint_as_float(((unsigned)h) << 16);
}

__device__ __forceinline__ float wave_sum(float v) {
    #pragma unroll
    for (int s = 1; s < 64; s <<= 1) v += __shfl_xor(v, s, 64);
    return v;
}

__device__ __forceinline__ void load_lds16(const void* g, void* l) {
    __builtin_amdgcn_global_load_lds(
        (const __attribute__((address_space(1))) void*)g,
        (__attribute__((address_space(3))) void*)l, 16, 0, 0);
}

// ---------------- kernel 1: norms, cos_ema, fp8 xq (x_n*16) + bf16 gelu ----------------
__global__ __launch_bounds__(256) void prep_kernel(
    const float* __restrict__ x, const float* __restrict__ ema,
    char* __restrict__ slots, float* __restrict__ cosema)
{
    const int wave = threadIdx.x >> 6;
    const int lane = threadIdx.x & 63;
    const int row  = blockIdx.x * 4 + wave; // 0 .. B*T-1

    const float* xr = x + (size_t)row * DDIM + lane * 8;
    float4 v0 = *reinterpret_cast<const float4*>(xr);
    float4 v1 = *reinterpret_cast<const float4*>(xr + 4);
    const float* er = ema + lane * 8;
    float4 e0 = *reinterpret_cast<const float4*>(er);
    float4 e1 = *reinterpret_cast<const float4*>(er + 4);

    float vx[8] = {v0.x,v0.y,v0.z,v0.w,v1.x,v1.y,v1.z,v1.w};
    float ve[8] = {e0.x,e0.y,e0.z,e0.w,e1.x,e1.y,e1.z,e1.w};
    float gg[8];

    float ssx=0.f, ssg=0.f, dge=0.f, sse=0.f;
    #pragma unroll
    for (int j=0;j<8;++j) {
        float xv = vx[j];
        ssx += xv*xv;
        float gv = gelu_f(xv);
        gg[j] = gv;
        ssg += gv*gv;
        dge += gv*ve[j];
        sse += ve[j]*ve[j];
    }
    ssx = wave_sum(ssx); ssg = wave_sum(ssg);
    dge = wave_sum(dge); sse = wave_sum(sse);

    // quantize x_n * 16 to e4m3 (MX scale 2^-4 per operand restores the product)
    float invx16 = 16.0f / fmaxf(sqrtf(ssx), 1e-12f);
    float s[8];
    #pragma unroll
    for (int j=0;j<8;++j) s[j] = vx[j] * invx16;
    int q0 = __builtin_amdgcn_cvt_pk_fp8_f32(s[0], s[1], 0, false);
    q0     = __builtin_amdgcn_cvt_pk_fp8_f32(s[2], s[3], q0, true);
    int q1 = __builtin_amdgcn_cvt_pk_fp8_f32(s[4], s[5], 0, false);
    q1     = __builtin_amdgcn_cvt_pk_fp8_f32(s[6], s[7], q1, true);

    char* rowb = slots + (size_t)row * SLOTB;
    reinterpret_cast<int*>(rowb)[lane*2]     = q0;   // xq bytes [0,512)
    reinterpret_cast<int*>(rowb)[lane*2 + 1] = q1;

    u16x8 hg;
    #pragma unroll
    for (int j=0;j<8;++j) hg[j] = f2bf(gg[j]);
    *reinterpret_cast<u16x8*>(rowb + 512 + lane * 16) = hg;  // gelu bytes [512,1536)

    if (lane == 0) {
        float c = dge / (fmaxf(sqrtf(ssg), 1e-12f) * fmaxf(sqrtf(sse), 1e-12f));
        c = fminf(fmaxf(c, -1.0f), 1.0f);
        cosema[row] = c;
    }
}

// -------- kernel 2: Xn*Xn^T row-max via MX-fp8 K=128, TWO tile-pairs / block --------
// Round-8 structure (known-good: dbuf issue-early, 2 blocks/CU, T1 batch-per-
// XCD, source-granule XOR involution) with the 4-iter fixed costs amortized:
// each block runs (rt,ct0) then (rt,ct0+1) through ONE continuous 8-iter dbuf
// pipeline (B pointer switches at iter 4; A re-staged L2-hot). Row-max folds
// across both pairs into slot ct0; slot ct1 gets a -2 filler (max-semantics
// preserved; each (slot,row-range) of part written exactly once).
__global__ __launch_bounds__(256) void simmax_kernel(
    const char* __restrict__ slots, float* __restrict__ part)
{
    __shared__ unsigned char sA[2][128*128];   // 128 rows x 128 B (fp8 K-step 128)
    __shared__ unsigned char sB[2][128*128];
    __shared__ float prow[2][128];
    __shared__ float pcol[2][2][128];          // [pair][wm][col]

    const int tid  = threadIdx.x;
    const int lane = tid & 63;
    const int w    = tid >> 6;
    const int wm   = w >> 1, wn = w & 1;

    const int b = blockIdx.x & 7;        // batch == XCD (round-robin dispatch)
    // decode (rt, chunk) from unit index; cnt(rt) = ceil((NT-rt)/2) = (17-rt)>>1
    int rem = blockIdx.x >> 3, rt = 0;
    while (rem >= ((17 - rt) >> 1)) { rem -= (17 - rt) >> 1; ++rt; }
    const int ct0  = rt + rem * 2;
    const int has2 = (ct0 + 1) < NT;
    const int ct1  = has2 ? (ct0 + 1) : ct0;

    const char* Ag  = slots + ((size_t)b * TDIM + (size_t)rt  * 128) * SLOTB;
    const char* Bg0 = slots + ((size_t)b * TDIM + (size_t)ct0 * 128) * SLOTB;
    const char* Bg1 = slots + ((size_t)b * TDIM + (size_t)ct1 * 128) * SLOTB;

    const int srow  = tid >> 3;                                // 0..31 within chunk
    const int scolb = (((tid & 7) ^ ((tid >> 3) & 7))) * 16;   // pre-swizzled src granule (bytes)
    const int NIT   = has2 ? 8 : 4;

    auto stage = [&](int buf, int it) {
        const int kb = (it & 3) * 128;                 // K-step byte offset
        const char* Bsrc = (it < 4) ? Bg0 : Bg1;
        #pragma unroll
        for (int i = 0; i < 4; ++i) {
            load_lds16(Ag   + (size_t)(i*32 + srow) * SLOTB + kb + scolb, &sA[buf][i*4096 + w*1024]);
            load_lds16(Bsrc + (size_t)(i*32 + srow) * SLOTB + kb + scolb, &sB[buf][i*4096 + w*1024]);
        }
    };

    f32x4 zero = {0.f, 0.f, 0.f, 0.f};
    f32x4 acc[4][4];
    #pragma unroll
    for (int m=0;m<4;++m)
        #pragma unroll
        for (int n=0;n<4;++n) acc[m][n] = zero;

    float rmax[4][4];    // folded row-max across both pairs (diag-masked)
    float cmax[2][4];    // per-pair col-max
    #pragma unroll
    for (int m=0;m<4;++m)
        #pragma unroll
        for (int r=0;r<4;++r) rmax[m][r] = -2.0f;
    #pragma unroll
    for (int p=0;p<2;++p)
        #pragma unroll
        for (int n=0;n<4;++n) cmax[p][n] = -2.0f;

    const int roff  = lane & 15;
    const int sw    = roff & 7;          // read-side XOR (row&7 == roff&7)
    const int klane = lane >> 4;
    const int g0 = ((2*klane)     ^ sw) * 16;   // two 16-B granules per 32-B fragment
    const int g1 = ((2*klane + 1) ^ sw) * 16;

    stage(0, 0);
    __syncthreads();                     // buf0 ready

    for (int it = 0; it < NIT; ++it) {
        const int cur = it & 1;
        if (it + 1 < NIT) stage(cur ^ 1, it + 1);    // issue-early: hides under MFMA

        i32x8 af[4], bf[4];
        #pragma unroll
        for (int m=0;m<4;++m) {
            const int base = (wm*64 + m*16 + roff) * 128;
            i32x4 lo = *reinterpret_cast<const i32x4*>(&sA[cur][base + g0]);
            i32x4 hi = *reinterpret_cast<const i32x4*>(&sA[cur][base + g1]);
            af[m] = __builtin_shufflevector(lo, hi, 0,1,2,3,4,5,6,7);
        }
        #pragma unroll
        for (int n=0;n<4;++n) {
            const int base = (wn*64 + n*16 + roff) * 128;
            i32x4 lo = *reinterpret_cast<const i32x4*>(&sB[cur][base + g0]);
            i32x4 hi = *reinterpret_cast<const i32x4*>(&sB[cur][base + g1]);
            bf[n] = __builtin_shufflevector(lo, hi, 0,1,2,3,4,5,6,7);
        }
        #pragma unroll
        for (int m=0;m<4;++m)
            #pragma unroll
            for (int n=0;n<4;++n)
                acc[m][n] = __builtin_amdgcn_mfma_scale_f32_16x16x128_f8f6f4(
                    af[m], bf[n], acc[m][n], 0, 0,
                    0, SCALE_E8M0, 0, SCALE_E8M0);

        if ((it & 3) == 3) {
            // pair complete: fold into rmax/cmax, reset acc for next pair.
            // C/D layout (m89/m91, shape-determined per m128):
            //   col = lane&15, row = (lane>>4)*4 + reg
            const int p   = (it < 4) ? 0 : 1;
            const int ctp = (it < 4) ? ct0 : ct1;
            const int gr0 = rt*128  + wm*64;
            const int gcb = ctp*128 + wn*64;
            #pragma unroll
            for (int m=0;m<4;++m) {
                #pragma unroll
                for (int r=0;r<4;++r) {
                    const int grow = gr0 + m*16 + ((lane>>4)<<2) + r;
                    #pragma unroll
                    for (int n=0;n<4;++n) {
                        const int gcol = gcb + n*16 + roff;
                        float v = acc[m][n][r];
                        cmax[p][n] = fmaxf(cmax[p][n], v);
                        // grow==gcol only possible on the diagonal tile (ranges
                        // disjoint when rt != ctp) -> masks exactly the diagonal
                        rmax[m][r] = fmaxf(rmax[m][r], (grow == gcol) ? -2.0f : v);
                    }
                }
            }
            if (it + 1 < NIT) {
                #pragma unroll
                for (int m=0;m<4;++m)
                    #pragma unroll
                    for (int n=0;n<4;++n) acc[m][n] = zero;
            }
        }
        __syncthreads();                 // next-tile loads drained + read/overwrite fence
    }

    // ---- end epilogue: shuffle reductions + part writes ----
    // row-max: butterfly across the 16-lane column group
    #pragma unroll
    for (int s = 1; s < 16; s <<= 1) {
        #pragma unroll
        for (int m=0;m<4;++m)
            #pragma unroll
            for (int r=0;r<4;++r)
                rmax[m][r] = fmaxf(rmax[m][r], __shfl_xor(rmax[m][r], s, 64));
    }
    if ((lane & 15) == 0) {
        #pragma unroll
        for (int m=0;m<4;++m)
            #pragma unroll
            for (int r=0;r<4;++r)
                prow[wn][wm*64 + m*16 + ((lane>>4)<<2) + r] = rmax[m][r];
    }
    // col-max: butterfly across the 4 row-groups
    #pragma unroll
    for (int s = 16; s < 64; s <<= 1) {
        #pragma unroll
        for (int p=0;p<2;++p)
            #pragma unroll
            for (int n=0;n<4;++n)
                cmax[p][n] = fmaxf(cmax[p][n], __shfl_xor(cmax[p][n], s, 64));
    }
    if (lane < 16) {
        #pragma unroll
        for (int p=0;p<2;++p)
            #pragma unroll
            for (int n=0;n<4;++n)
                pcol[p][wm][wn*64 + n*16 + lane] = cmax[p][n];
    }
    __syncthreads();
    if (tid < 128) {
        // folded row-max (both pairs) -> slot ct0; filler -> slot ct1
        float rv = fmaxf(prow[0][tid], prow[1][tid]);
        part[((size_t)b*NT + ct0)*TDIM + (size_t)rt*128 + tid] = rv;
        if (has2)
            part[((size_t)b*NT + ct1)*TDIM + (size_t)rt*128 + tid] = -2.0f;
        // col-max per pair -> slot rt at the pair's column rows
        if (rt != ct0) {
            float cv = fmaxf(pcol[0][0][tid], pcol[0][1][tid]);
            part[((size_t)b*NT + rt)*TDIM + (size_t)ct0*128 + tid] = cv;
        }
        if (has2) {
            float cv = fmaxf(pcol[1][0][tid], pcol[1][1][tid]);
            part[((size_t)b*NT + rt)*TDIM + (size_t)ct1*128 + tid] = cv;
        }
    }
}

// ---------------- kernel 3: gate * cached gelu ----------------
// slots aliases d_out: row r's slot bytes [0,512)=xq (dead), [512,1536)=gelu
// bf16. Each wave reads its own row's gelu then overwrites its own slot with
// the fp32 out row — load-before-store within the wave, race-free.
__global__ __launch_bounds__(256) void finalize_kernel(
    char* slots,
    const float* __restrict__ part, const float* __restrict__ cosema,
    const float* __restrict__ p_log_tau, const float* __restrict__ p_log_sigma,
    const float* __restrict__ p_log_w)
{
    const int wave = threadIdx.x >> 6;
    const int lane = threadIdx.x & 63;
    const int row  = blockIdx.x * 4 + wave;
    const int b = row >> 11;     // /2048
    const int t = row & 2047;

    const float tau   = __expf(p_log_tau[0]);
    const float sigma = log1pf(__expf(p_log_sigma[0])); // softplus
    const float wgt   = log1pf(__expf(p_log_w[0]));

    float nn = -2.0f;
    #pragma unroll
    for (int ctile = 0; ctile < NT; ++ctile)
        nn = fmaxf(nn, part[((size_t)b*NT + ctile)*TDIM + t]);
    nn = fminf(fmaxf(nn, -1.0f), 1.0f);

    const float novelty  = (1.0f - nn) * 0.5f;
    const float surprise = tanh_fast(sigma * novelty);
    const float gate = __expf(-tau * cosema[row]) * (1.0f + wgt * surprise);

    char* rowb = slots + (size_t)row * SLOTB;
    u16x8 hg = *reinterpret_cast<const u16x8*>(rowb + 512 + lane * 16);
    float4 o0, o1;
    o0.x = bf2f(hg[0]) * gate; o0.y = bf2f(hg[1]) * gate;
    o0.z = bf2f(hg[2]) * gate; o0.w = bf2f(hg[3]) * gate;
    o1.x = bf2f(hg[4]) * gate; o1.y = bf2f(hg[5]) * gate;
    o1.z = bf2f(hg[6]) * gate; o1.w = bf2f(hg[7]) * gate;
    float* orow = reinterpret_cast<float*>(rowb) + lane * 8;
    *reinterpret_cast<float4*>(orow)     = o0;
    *reinterpret_cast<float4*>(orow + 4) = o1;
}

extern "C" void kernel_launch(void* const* d_in, const int* in_sizes, int n_in,
                              void* d_out, int out_size, void* d_ws, size_t ws_size,
                              hipStream_t stream) {
    const float* x           = (const float*)d_in[0];
    // d_in[1] = logit_decay (unused by reference)
    const float* p_log_tau   = (const float*)d_in[2];
    const float* p_log_sigma = (const float*)d_in[3];
    const float* p_log_w     = (const float*)d_in[4];
    const float* ema         = (const float*)d_in[5];

    // d_out doubles as scratch: per-row 2048-B slots hold [fp8 xq | bf16 gelu]
    // until finalize overwrites each slot with the fp32 output row.
    char*  slots  = (char*)d_out;                      // B*T*SLOTB = 33.6 MB
    float* part   = (float*)d_ws;                      // B*NT*T*4 = 2 MB
    float* cosema = (float*)((char*)d_ws + (size_t)BATCH*NT*TDIM*sizeof(float));

    prep_kernel<<<dim3(BATCH*TDIM/4), 256, 0, stream>>>(x, ema, slots, cosema);
    simmax_kernel<<<dim3(NUNITS*BATCH), 256, 0, stream>>>(slots, part);
    finalize_kernel<<<dim3(BATCH*TDIM/4), 256, 0, stream>>>(
        slots, part, cosema, p_log_tau, p_log_sigma, p_log_w);
}